// Round 1
// baseline (3165.487 us; speedup 1.0000x reference)
//
#include <hip/hip_runtime.h>
#include <hip/hip_bf16.h>

// GAT 3-layer: N=50000 nodes, E=800000 edges, H=6 heads.
// Strategy: CSR-by-dst built per call; dst-centric atomic-free aggregation.

#define HHEADS 6

__device__ __forceinline__ unsigned fkey(float f) {
    unsigned u = __float_as_uint(f);
    return (u >> 31) ? ~u : (u | 0x80000000u);
}
__device__ __forceinline__ float funkey(unsigned k) {
    return (k >> 31) ? __uint_as_float(k & 0x7fffffffu) : __uint_as_float(~k);
}

// ---------------- CSR build ----------------
__global__ void hist_kernel(const int* __restrict__ dst, int* __restrict__ count, int E) {
    int e = blockIdx.x * blockDim.x + threadIdx.x;
    if (e >= E) return;
    atomicAdd(&count[dst[e]], 1);
}

__global__ void scan_kernel(const int* __restrict__ count, int* __restrict__ offsets,
                            int n, int total) {
    __shared__ int sdata[1024];
    __shared__ int sbase;
    if (threadIdx.x == 0) sbase = 0;
    __syncthreads();
    int nchunks = (n + 1023) / 1024;
    for (int ch = 0; ch < nchunks; ++ch) {
        int i = ch * 1024 + threadIdx.x;
        int v = (i < n) ? count[i] : 0;
        int base = sbase;
        sdata[threadIdx.x] = v;
        __syncthreads();
        for (int off = 1; off < 1024; off <<= 1) {
            int tmp = (threadIdx.x >= (unsigned)off) ? sdata[threadIdx.x - off] : 0;
            __syncthreads();
            sdata[threadIdx.x] += tmp;
            __syncthreads();
        }
        int incl = sdata[threadIdx.x];
        if (i < n) offsets[i] = base + (incl - v);
        __syncthreads();
        if (threadIdx.x == 1023) sbase = base + sdata[1023];
        __syncthreads();
    }
    if (threadIdx.x == 0) offsets[n] = total;
}

__global__ void scatter_kernel(const int* __restrict__ src, const int* __restrict__ dst,
                               const int* __restrict__ offsets, int* __restrict__ cursor,
                               int* __restrict__ ssrc, int* __restrict__ seid, int E) {
    int e = blockIdx.x * blockDim.x + threadIdx.x;
    if (e >= E) return;
    int d = dst[e];
    int pos = offsets[d] + atomicAdd(&cursor[d], 1);
    ssrc[pos] = src[e];
    seid[pos] = e;
}

// ---------------- per-layer kernels ----------------
// was[hd*FIN+k] = sum_f W[hd,k,f]*a_s[hd,f]  (folds es = x . was)
__global__ void prep_attn(const float* __restrict__ W, const float* __restrict__ as_,
                          const float* __restrict__ ad_, float* __restrict__ was,
                          float* __restrict__ wad, int FIN, int F) {
    int i = blockIdx.x * blockDim.x + threadIdx.x;
    if (i >= HHEADS * FIN) return;
    int hd = i / FIN, k = i % FIN;
    float s = 0.f, d = 0.f;
    const float* Wp = W + (hd * FIN + k) * F;
    for (int f = 0; f < F; ++f) {
        float w = Wp[f];
        s += w * as_[hd * F + f];
        d += w * ad_[hd * F + f];
    }
    was[i] = s;
    wad[i] = d;
}

// block = 6*F threads, one block per node. h[n, hd*F+f] = sum_k x[n,k] W[hd,k,f]
template <int FIN, int F>
__global__ void transform_kernel(const float* __restrict__ x, const float* __restrict__ W,
                                 const float* __restrict__ was, const float* __restrict__ wad,
                                 float* __restrict__ h, float* __restrict__ es,
                                 float* __restrict__ ed) {
    constexpr int HF = HHEADS * F;
    __shared__ float xs[FIN];
    int node = blockIdx.x;
    int t = threadIdx.x;
    for (int k = t; k < FIN; k += HF) xs[k] = x[(size_t)node * FIN + k];
    __syncthreads();
    int hd = t / F, f = t % F;
    const float* Wp = W + (size_t)(hd * FIN) * F + f;
    float acc = 0.f;
    for (int k = 0; k < FIN; ++k) acc += xs[k] * Wp[(size_t)k * F];
    h[(size_t)node * HF + t] = acc;
    if (t < 2 * HHEADS) {
        int hh = t % HHEADS;
        bool isd = (t >= HHEADS);
        const float* wv = (isd ? wad : was) + hh * FIN;
        float s = 0.f;
        for (int k = 0; k < FIN; ++k) s += xs[k] * wv[k];
        (isd ? ed : es)[(size_t)node * HHEADS + hh] = s;
    }
}

__global__ void edge_logits(const int* __restrict__ src, const int* __restrict__ dst,
                            const float* __restrict__ es, const float* __restrict__ ed,
                            float* __restrict__ eedge, unsigned* __restrict__ emax, int E) {
    int e = blockIdx.x * blockDim.x + threadIdx.x;
    if (e >= E) return;
    int s = src[e], d = dst[e];
#pragma unroll
    for (int hd = 0; hd < HHEADS; ++hd) {
        float v = es[s * HHEADS + hd] + ed[d * HHEADS + hd];
        v = v > 0.f ? v : 0.2f * v;  // leaky relu 0.2
        eedge[(size_t)e * HHEADS + hd] = v;
        atomicMax(&emax[d * HHEADS + hd], fkey(v));
    }
}

__global__ void edge_exp(const int* __restrict__ dst, float* __restrict__ eedge,
                         const unsigned* __restrict__ emax, float* __restrict__ denom, int E) {
    int e = blockIdx.x * blockDim.x + threadIdx.x;
    if (e >= E) return;
    int d = dst[e];
#pragma unroll
    for (int hd = 0; hd < HHEADS; ++hd) {
        float m = funkey(emax[d * HHEADS + hd]);
        float ex = expf(eedge[(size_t)e * HHEADS + hd] - m);
        eedge[(size_t)e * HHEADS + hd] = ex;
        atomicAdd(&denom[d * HHEADS + hd], ex);
    }
}

// thread per (node, channel c in [0,6F)); atomic-free accumulation over CSR row.
template <int F>
__global__ void aggregate_kernel(const float* __restrict__ h, const float* __restrict__ ex,
                                 const float* __restrict__ denom,
                                 const int* __restrict__ offsets, const int* __restrict__ ssrc,
                                 const int* __restrict__ seid, float* __restrict__ out, int n) {
    constexpr int HF = HHEADS * F;
    int tid = blockIdx.x * blockDim.x + threadIdx.x;
    if (tid >= n * HF) return;
    int node = tid / HF, c = tid % HF;
    int hd = c / F;
    float invd = 1.0f / (denom[node * HHEADS + hd] + 1e-16f);
    int a = offsets[node], b = offsets[node + 1];
    float acc = 0.f;
    for (int j = a; j < b; ++j) {
        int s = ssrc[j];
        int eid = seid[j];
        acc += ex[(size_t)eid * HHEADS + hd] * h[(size_t)s * HF + c];
    }
    acc *= invd;
    out[tid] = acc > 0.f ? acc : (expf(acc) - 1.0f);  // elu
}

// ---------------- pooling + head ----------------
__global__ void pool_kernel(const float* __restrict__ out3, float* __restrict__ g, int n) {
    int b = blockIdx.x, t = threadIdx.x;
    int chunk = (n + gridDim.x - 1) / gridDim.x;
    int n0 = b * chunk, n1 = min(n, n0 + chunk);
    float a0 = 0.f, a1 = 0.f;
    for (int node = n0; node < n1; ++node) {
        a0 += out3[(size_t)node * 384 + t];
        if (t < 128) a1 += out3[(size_t)node * 384 + 256 + t];
    }
    atomicAdd(&g[t], a0);
    if (t < 128) atomicAdd(&g[256 + t], a1);
}

__global__ void final_kernel(const float* __restrict__ g, const float* __restrict__ Wd,
                             const float* __restrict__ bd, float* __restrict__ outp) {
    __shared__ float red[384];
    int t = threadIdx.x;  // blockDim = 384
    float v = g[t];
    red[t] = v * v;
    __syncthreads();
    for (int s = 192; s >= 3; s >>= 1) {
        if (t < s) red[t] += red[t + s];
        __syncthreads();
    }
    __shared__ float scale_s;
    if (t == 0) {
        float norm = sqrtf(red[0] + red[1] + red[2]);
        scale_s = 1.0f / fmaxf(norm, 1e-12f);
    }
    __syncthreads();
    float scale = scale_s;
    red[t] = v * scale * Wd[t];
    __syncthreads();
    for (int s = 192; s >= 3; s >>= 1) {
        if (t < s) red[t] += red[t + s];
        __syncthreads();
    }
    if (t == 0) outp[0] = red[0] + red[1] + red[2] + bd[0];
}

// ---------------- host side ----------------
template <int FIN, int F>
static void run_layer(const float* xin, const float* W, const float* as_, const float* ad_,
                      float* hbuf, float* outbuf, float* es, float* ed, unsigned* emax,
                      float* denom, float* eedge, float* was, float* wad, const int* src,
                      const int* dst, const int* offsets, const int* ssrc, const int* seid,
                      int N, int E, hipStream_t stream) {
    constexpr int HF = HHEADS * F;
    prep_attn<<<(HHEADS * FIN + 63) / 64, 64, 0, stream>>>(W, as_, ad_, was, wad, FIN, F);
    transform_kernel<FIN, F><<<N, HF, 0, stream>>>(xin, W, was, wad, hbuf, es, ed);
    hipMemsetAsync(emax, 0, (size_t)N * HHEADS * 4, stream);
    hipMemsetAsync(denom, 0, (size_t)N * HHEADS * 4, stream);
    edge_logits<<<(E + 255) / 256, 256, 0, stream>>>(src, dst, es, ed, eedge, emax, E);
    edge_exp<<<(E + 255) / 256, 256, 0, stream>>>(dst, eedge, emax, denom, E);
    long total = (long)N * HF;
    aggregate_kernel<F><<<(total + 255) / 256, 256, 0, stream>>>(hbuf, eedge, denom, offsets,
                                                                 ssrc, seid, outbuf, N);
}

extern "C" void kernel_launch(void* const* d_in, const int* in_sizes, int n_in, void* d_out,
                              int out_size, void* d_ws, size_t ws_size, hipStream_t stream) {
    const float* x = (const float*)d_in[0];
    const int* ei = (const int*)d_in[1];
    const float* W1 = (const float*)d_in[2];
    const float* a1s = (const float*)d_in[3];
    const float* a1d = (const float*)d_in[4];
    const float* W2 = (const float*)d_in[5];
    const float* a2s = (const float*)d_in[6];
    const float* a2d = (const float*)d_in[7];
    const float* W3 = (const float*)d_in[8];
    const float* a3s = (const float*)d_in[9];
    const float* a3d = (const float*)d_in[10];
    const float* Wd = (const float*)d_in[11];
    const float* bd = (const float*)d_in[12];
    float* outp = (float*)d_out;

    const int N = in_sizes[0] / 11;
    const int E = in_sizes[1] / 2;
    const int* src = ei;
    const int* dst = ei + E;

    char* w = (char*)d_ws;
    size_t off = 0;
    auto A = [&](size_t bytes) {
        size_t o = off;
        off += (bytes + 255) & ~(size_t)255;
        return o;
    };
    float* bufH = (float*)(w + A((size_t)N * 384 * 4));
    float* bufA = (float*)(w + A((size_t)N * 384 * 4));  // layer1 out (96), layer3 out (384)
    float* bufB = (float*)(w + A((size_t)N * 192 * 4));  // layer2 out
    float* es = (float*)(w + A((size_t)N * HHEADS * 4));
    float* ed = (float*)(w + A((size_t)N * HHEADS * 4));
    unsigned* emax = (unsigned*)(w + A((size_t)N * HHEADS * 4));
    float* denom = (float*)(w + A((size_t)N * HHEADS * 4));
    float* eedge = (float*)(w + A((size_t)E * HHEADS * 4));
    float* was = (float*)(w + A(HHEADS * 192 * 4));
    float* wad = (float*)(w + A(HHEADS * 192 * 4));
    int* count = (int*)(w + A((size_t)(N + 1) * 4));
    int* cursor = (int*)(w + A((size_t)(N + 1) * 4));
    int* offsets = (int*)(w + A((size_t)(N + 1) * 4));
    int* ssrc = (int*)(w + A((size_t)E * 4));
    int* seid = (int*)(w + A((size_t)E * 4));
    float* g = (float*)(w + A(384 * 4));

    // CSR build (by dst)
    hipMemsetAsync(count, 0, (size_t)N * 4, stream);
    hipMemsetAsync(cursor, 0, (size_t)N * 4, stream);
    hist_kernel<<<(E + 255) / 256, 256, 0, stream>>>(dst, count, E);
    scan_kernel<<<1, 1024, 0, stream>>>(count, offsets, N, E);
    scatter_kernel<<<(E + 255) / 256, 256, 0, stream>>>(src, dst, offsets, cursor, ssrc, seid, E);

    // 3 GAT layers
    run_layer<11, 16>(x, W1, a1s, a1d, bufH, bufA, es, ed, emax, denom, eedge, was, wad, src,
                      dst, offsets, ssrc, seid, N, E, stream);
    run_layer<96, 32>(bufA, W2, a2s, a2d, bufH, bufB, es, ed, emax, denom, eedge, was, wad, src,
                      dst, offsets, ssrc, seid, N, E, stream);
    run_layer<192, 64>(bufB, W3, a3s, a3d, bufH, bufA, es, ed, emax, denom, eedge, was, wad, src,
                       dst, offsets, ssrc, seid, N, E, stream);

    // sum-pool -> normalize -> dense
    hipMemsetAsync(g, 0, 384 * 4, stream);
    pool_kernel<<<256, 256, 0, stream>>>(bufA, g, N);
    final_kernel<<<1, 384, 0, stream>>>(g, Wd, bd, outp);
}

// Round 2
// 2677.597 us; speedup vs baseline: 1.1822x; 1.1822x over previous
//
#include <hip/hip_runtime.h>
#include <hip/hip_bf16.h>

// GAT 3-layer: N=50000 nodes, E=800000 edges, H=6 heads.
// CSR-by-dst built per call; dst-centric atomic-free aggregation.
// R1: transforms are now tiled f32 GEMMs (W re-read was L2-BW bound at 577us).

#define HHEADS 6

__device__ __forceinline__ unsigned fkey(float f) {
    unsigned u = __float_as_uint(f);
    return (u >> 31) ? ~u : (u | 0x80000000u);
}
__device__ __forceinline__ float funkey(unsigned k) {
    return (k >> 31) ? __uint_as_float(k & 0x7fffffffu) : __uint_as_float(~k);
}

// ---------------- CSR build ----------------
__global__ void hist_kernel(const int* __restrict__ dst, int* __restrict__ count, int E) {
    int e = blockIdx.x * blockDim.x + threadIdx.x;
    if (e >= E) return;
    atomicAdd(&count[dst[e]], 1);
}

__global__ void scan_kernel(const int* __restrict__ count, int* __restrict__ offsets,
                            int n, int total) {
    __shared__ int sdata[1024];
    __shared__ int sbase;
    if (threadIdx.x == 0) sbase = 0;
    __syncthreads();
    int nchunks = (n + 1023) / 1024;
    for (int ch = 0; ch < nchunks; ++ch) {
        int i = ch * 1024 + threadIdx.x;
        int v = (i < n) ? count[i] : 0;
        int base = sbase;
        sdata[threadIdx.x] = v;
        __syncthreads();
        for (int off = 1; off < 1024; off <<= 1) {
            int tmp = (threadIdx.x >= (unsigned)off) ? sdata[threadIdx.x - off] : 0;
            __syncthreads();
            sdata[threadIdx.x] += tmp;
            __syncthreads();
        }
        int incl = sdata[threadIdx.x];
        if (i < n) offsets[i] = base + (incl - v);
        __syncthreads();
        if (threadIdx.x == 1023) sbase = base + sdata[1023];
        __syncthreads();
    }
    if (threadIdx.x == 0) offsets[n] = total;
}

__global__ void scatter_kernel(const int* __restrict__ src, const int* __restrict__ dst,
                               const int* __restrict__ offsets, int* __restrict__ cursor,
                               int* __restrict__ ssrc, int* __restrict__ seid, int E) {
    int e = blockIdx.x * blockDim.x + threadIdx.x;
    if (e >= E) return;
    int d = dst[e];
    int pos = offsets[d] + atomicAdd(&cursor[d], 1);
    ssrc[pos] = src[e];
    seid[pos] = e;
}

// ---------------- transform: tiled f32 GEMM ----------------
// Wp[k*HF + hd*F + f] = W[hd, k, f]
__global__ void repack_w(const float* __restrict__ W, float* __restrict__ Wp, int FIN, int F) {
    int HF = HHEADS * F;
    int i = blockIdx.x * blockDim.x + threadIdx.x;
    if (i >= FIN * HF) return;
    int k = i / HF, c = i % HF;
    int hd = c / F, f = c % F;
    Wp[i] = W[(hd * FIN + k) * F + f];
}

// C[M,N] = A[M,K] @ B[K,N].  BM=BN=64, BK=32, 256 threads, 4x4 micro-tile.
template <int BM, int BN, int BK>
__global__ __launch_bounds__(256) void gemm_kernel(const float* __restrict__ A,
                                                   const float* __restrict__ B,
                                                   float* __restrict__ C, int M, int K, int N) {
    __shared__ float As[BK][BM + 4];  // +4 pad: rows stay 16B-aligned, breaks write conflicts
    __shared__ float Bs[BK][BN];
    int tid = threadIdx.x;
    int tx = tid % 16, ty = tid / 16;
    int m0 = blockIdx.y * BM, n0 = blockIdx.x * BN;
    float acc[4][4] = {};
    for (int kk0 = 0; kk0 < K; kk0 += BK) {
        // stage A (transposed into LDS): BM*BK floats, k-contiguous global reads
#pragma unroll
        for (int i = 0; i < (BM * BK) / 256; ++i) {
            int idx = tid + i * 256;
            int m = idx / BK, k = idx % BK;
            float v = 0.f;
            if (m0 + m < M && kk0 + k < K) v = A[(size_t)(m0 + m) * K + kk0 + k];
            As[k][m] = v;
        }
        // stage B: BK*BN floats as float4
#pragma unroll
        for (int i = 0; i < (BK * BN) / 1024; ++i) {
            int idx = tid + i * 256;
            int k = idx / (BN / 4), n4 = idx % (BN / 4);
            float4 v = make_float4(0.f, 0.f, 0.f, 0.f);
            if (kk0 + k < K && n0 + n4 * 4 < N)
                v = *(const float4*)&B[(size_t)(kk0 + k) * N + n0 + n4 * 4];
            *(float4*)&Bs[k][n4 * 4] = v;
        }
        __syncthreads();
#pragma unroll
        for (int k = 0; k < BK; ++k) {
            float4 av = *(const float4*)&As[k][ty * 4];
            float4 bv = *(const float4*)&Bs[k][tx * 4];
            float a[4] = {av.x, av.y, av.z, av.w};
            float b[4] = {bv.x, bv.y, bv.z, bv.w};
#pragma unroll
            for (int i = 0; i < 4; ++i)
#pragma unroll
                for (int j = 0; j < 4; ++j) acc[i][j] += a[i] * b[j];
        }
        __syncthreads();
    }
#pragma unroll
    for (int i = 0; i < 4; ++i) {
        int m = m0 + ty * 4 + i;
        if (m < M && n0 + tx * 4 < N) {
            float4 v = make_float4(acc[i][0], acc[i][1], acc[i][2], acc[i][3]);
            *(float4*)&C[(size_t)m * N + n0 + tx * 4] = v;
        }
    }
}

// es[n,hd] = sum_f h[n,hd,f]*a_s[hd,f]; block = HF threads, one node per block.
template <int F>
__global__ void attn_terms(const float* __restrict__ h, const float* __restrict__ as_,
                           const float* __restrict__ ad_, float* __restrict__ es,
                           float* __restrict__ ed) {
    constexpr int HF = HHEADS * F;
    int node = blockIdx.x;
    int t = threadIdx.x;
    float v = h[(size_t)node * HF + t];
    float s = v * as_[t];
    float d = v * ad_[t];
#pragma unroll
    for (int off = F / 2; off > 0; off >>= 1) {
        s += __shfl_down(s, off, F);
        d += __shfl_down(d, off, F);
    }
    if ((t & (F - 1)) == 0) {
        int hd = t / F;
        es[node * HHEADS + hd] = s;
        ed[node * HHEADS + hd] = d;
    }
}

// ---------------- edge kernels ----------------
__global__ void edge_logits(const int* __restrict__ src, const int* __restrict__ dst,
                            const float* __restrict__ es, const float* __restrict__ ed,
                            float* __restrict__ eedge, unsigned* __restrict__ emax, int E) {
    int e = blockIdx.x * blockDim.x + threadIdx.x;
    if (e >= E) return;
    int s = src[e], d = dst[e];
#pragma unroll
    for (int hd = 0; hd < HHEADS; ++hd) {
        float v = es[s * HHEADS + hd] + ed[d * HHEADS + hd];
        v = v > 0.f ? v : 0.2f * v;  // leaky relu 0.2
        eedge[(size_t)e * HHEADS + hd] = v;
        atomicMax(&emax[d * HHEADS + hd], fkey(v));
    }
}

__global__ void edge_exp(const int* __restrict__ dst, float* __restrict__ eedge,
                         const unsigned* __restrict__ emax, float* __restrict__ denom, int E) {
    int e = blockIdx.x * blockDim.x + threadIdx.x;
    if (e >= E) return;
    int d = dst[e];
#pragma unroll
    for (int hd = 0; hd < HHEADS; ++hd) {
        float m = funkey(emax[d * HHEADS + hd]);
        float ex = expf(eedge[(size_t)e * HHEADS + hd] - m);
        eedge[(size_t)e * HHEADS + hd] = ex;
        atomicAdd(&denom[d * HHEADS + hd], ex);
    }
}

// thread per (node, channel); atomic-free accumulation over CSR row.
template <int F>
__global__ void aggregate_kernel(const float* __restrict__ h, const float* __restrict__ ex,
                                 const float* __restrict__ denom,
                                 const int* __restrict__ offsets, const int* __restrict__ ssrc,
                                 const int* __restrict__ seid, float* __restrict__ out, int n) {
    constexpr int HF = HHEADS * F;
    int tid = blockIdx.x * blockDim.x + threadIdx.x;
    if (tid >= n * HF) return;
    int node = tid / HF, c = tid % HF;
    int hd = c / F;
    float invd = 1.0f / (denom[node * HHEADS + hd] + 1e-16f);
    int a = offsets[node], b = offsets[node + 1];
    float acc = 0.f;
    for (int j = a; j < b; ++j) {
        int s = ssrc[j];
        int eid = seid[j];
        acc += ex[(size_t)eid * HHEADS + hd] * h[(size_t)s * HF + c];
    }
    acc *= invd;
    out[tid] = acc > 0.f ? acc : (expf(acc) - 1.0f);  // elu
}

// ---------------- pooling + head ----------------
__global__ void pool_kernel(const float* __restrict__ out3, float* __restrict__ g, int n) {
    int b = blockIdx.x, t = threadIdx.x;
    int chunk = (n + gridDim.x - 1) / gridDim.x;
    int n0 = b * chunk, n1 = min(n, n0 + chunk);
    float a0 = 0.f, a1 = 0.f;
    for (int node = n0; node < n1; ++node) {
        a0 += out3[(size_t)node * 384 + t];
        if (t < 128) a1 += out3[(size_t)node * 384 + 256 + t];
    }
    atomicAdd(&g[t], a0);
    if (t < 128) atomicAdd(&g[256 + t], a1);
}

__global__ void final_kernel(const float* __restrict__ g, const float* __restrict__ Wd,
                             const float* __restrict__ bd, float* __restrict__ outp) {
    __shared__ float red[384];
    int t = threadIdx.x;  // blockDim = 384
    float v = g[t];
    red[t] = v * v;
    __syncthreads();
    for (int s = 192; s >= 3; s >>= 1) {
        if (t < s) red[t] += red[t + s];
        __syncthreads();
    }
    __shared__ float scale_s;
    if (t == 0) {
        float norm = sqrtf(red[0] + red[1] + red[2]);
        scale_s = 1.0f / fmaxf(norm, 1e-12f);
    }
    __syncthreads();
    float scale = scale_s;
    red[t] = v * scale * Wd[t];
    __syncthreads();
    for (int s = 192; s >= 3; s >>= 1) {
        if (t < s) red[t] += red[t + s];
        __syncthreads();
    }
    if (t == 0) outp[0] = red[0] + red[1] + red[2] + bd[0];
}

// ---------------- host side ----------------
template <int FIN, int F>
static void run_layer(const float* xin, const float* W, const float* as_, const float* ad_,
                      float* wp, float* hbuf, float* outbuf, float* es, float* ed,
                      unsigned* emax, float* denom, float* eedge, const int* src,
                      const int* dst, const int* offsets, const int* ssrc, const int* seid,
                      int N, int E, hipStream_t stream) {
    constexpr int HF = HHEADS * F;
    repack_w<<<(FIN * HF + 255) / 256, 256, 0, stream>>>(W, wp, FIN, F);
    dim3 grid((HF + 63) / 64, (N + 63) / 64);
    gemm_kernel<64, 64, 32><<<grid, 256, 0, stream>>>(xin, wp, hbuf, N, FIN, HF);
    attn_terms<F><<<N, HF, 0, stream>>>(hbuf, as_, ad_, es, ed);
    hipMemsetAsync(emax, 0, (size_t)N * HHEADS * 4, stream);
    hipMemsetAsync(denom, 0, (size_t)N * HHEADS * 4, stream);
    edge_logits<<<(E + 255) / 256, 256, 0, stream>>>(src, dst, es, ed, eedge, emax, E);
    edge_exp<<<(E + 255) / 256, 256, 0, stream>>>(dst, eedge, emax, denom, E);
    long total = (long)N * HF;
    aggregate_kernel<F><<<(total + 255) / 256, 256, 0, stream>>>(hbuf, eedge, denom, offsets,
                                                                 ssrc, seid, outbuf, N);
}

extern "C" void kernel_launch(void* const* d_in, const int* in_sizes, int n_in, void* d_out,
                              int out_size, void* d_ws, size_t ws_size, hipStream_t stream) {
    const float* x = (const float*)d_in[0];
    const int* ei = (const int*)d_in[1];
    const float* W1 = (const float*)d_in[2];
    const float* a1s = (const float*)d_in[3];
    const float* a1d = (const float*)d_in[4];
    const float* W2 = (const float*)d_in[5];
    const float* a2s = (const float*)d_in[6];
    const float* a2d = (const float*)d_in[7];
    const float* W3 = (const float*)d_in[8];
    const float* a3s = (const float*)d_in[9];
    const float* a3d = (const float*)d_in[10];
    const float* Wd = (const float*)d_in[11];
    const float* bd = (const float*)d_in[12];
    float* outp = (float*)d_out;

    const int N = in_sizes[0] / 11;
    const int E = in_sizes[1] / 2;
    const int* src = ei;
    const int* dst = ei + E;

    char* w = (char*)d_ws;
    size_t off = 0;
    auto A = [&](size_t bytes) {
        size_t o = off;
        off += (bytes + 255) & ~(size_t)255;
        return o;
    };
    float* bufH = (float*)(w + A((size_t)N * 384 * 4));
    float* bufA = (float*)(w + A((size_t)N * 384 * 4));  // layer1 out (96), layer3 out (384)
    float* bufB = (float*)(w + A((size_t)N * 192 * 4));  // layer2 out
    float* es = (float*)(w + A((size_t)N * HHEADS * 4));
    float* ed = (float*)(w + A((size_t)N * HHEADS * 4));
    unsigned* emax = (unsigned*)(w + A((size_t)N * HHEADS * 4));
    float* denom = (float*)(w + A((size_t)N * HHEADS * 4));
    float* eedge = (float*)(w + A((size_t)E * HHEADS * 4));
    float* wp = (float*)(w + A((size_t)192 * 384 * 4));  // repacked W, max layer3
    int* count = (int*)(w + A((size_t)(N + 1) * 4));
    int* cursor = (int*)(w + A((size_t)(N + 1) * 4));
    int* offsets = (int*)(w + A((size_t)(N + 1) * 4));
    int* ssrc = (int*)(w + A((size_t)E * 4));
    int* seid = (int*)(w + A((size_t)E * 4));
    float* g = (float*)(w + A(384 * 4));

    // CSR build (by dst)
    hipMemsetAsync(count, 0, (size_t)N * 4, stream);
    hipMemsetAsync(cursor, 0, (size_t)N * 4, stream);
    hist_kernel<<<(E + 255) / 256, 256, 0, stream>>>(dst, count, E);
    scan_kernel<<<1, 1024, 0, stream>>>(count, offsets, N, E);
    scatter_kernel<<<(E + 255) / 256, 256, 0, stream>>>(src, dst, offsets, cursor, ssrc, seid, E);

    // 3 GAT layers
    run_layer<11, 16>(x, W1, a1s, a1d, wp, bufH, bufA, es, ed, emax, denom, eedge, src, dst,
                      offsets, ssrc, seid, N, E, stream);
    run_layer<96, 32>(bufA, W2, a2s, a2d, wp, bufH, bufB, es, ed, emax, denom, eedge, src, dst,
                      offsets, ssrc, seid, N, E, stream);
    run_layer<192, 64>(bufB, W3, a3s, a3d, wp, bufH, bufA, es, ed, emax, denom, eedge, src, dst,
                       offsets, ssrc, seid, N, E, stream);

    // sum-pool -> normalize -> dense
    hipMemsetAsync(g, 0, 384 * 4, stream);
    pool_kernel<<<256, 256, 0, stream>>>(bufA, g, N);
    final_kernel<<<1, 384, 0, stream>>>(g, Wd, bd, outp);
}

// Round 3
// 969.000 us; speedup vs baseline: 3.2668x; 2.7633x over previous
//
#include <hip/hip_runtime.h>
#include <hip/hip_bf16.h>

// GAT 3-layer: N=50000 nodes, E=800000 edges, H=6 heads.
// CSR-by-dst built per call; dst-centric atomic-free aggregation.
// R1: transforms = tiled f32 GEMMs (W re-read was L2-BW bound at 577us).
// R2: edge softmax is now dst-centric over CSR (zero atomics, alpha stored in
//     CSR order -> aggregate loses the seid indirection), aggregate float4.

#define HHEADS 6

// ---------------- CSR build ----------------
__global__ void hist_kernel(const int* __restrict__ dst, int* __restrict__ count, int E) {
    int e = blockIdx.x * blockDim.x + threadIdx.x;
    if (e >= E) return;
    atomicAdd(&count[dst[e]], 1);
}

__global__ void scan_kernel(const int* __restrict__ count, int* __restrict__ offsets,
                            int n, int total) {
    __shared__ int sdata[1024];
    __shared__ int sbase;
    if (threadIdx.x == 0) sbase = 0;
    __syncthreads();
    int nchunks = (n + 1023) / 1024;
    for (int ch = 0; ch < nchunks; ++ch) {
        int i = ch * 1024 + threadIdx.x;
        int v = (i < n) ? count[i] : 0;
        int base = sbase;
        sdata[threadIdx.x] = v;
        __syncthreads();
        for (int off = 1; off < 1024; off <<= 1) {
            int tmp = (threadIdx.x >= (unsigned)off) ? sdata[threadIdx.x - off] : 0;
            __syncthreads();
            sdata[threadIdx.x] += tmp;
            __syncthreads();
        }
        int incl = sdata[threadIdx.x];
        if (i < n) offsets[i] = base + (incl - v);
        __syncthreads();
        if (threadIdx.x == 1023) sbase = base + sdata[1023];
        __syncthreads();
    }
    if (threadIdx.x == 0) offsets[n] = total;
}

__global__ void scatter_kernel(const int* __restrict__ src, const int* __restrict__ dst,
                               const int* __restrict__ offsets, int* __restrict__ cursor,
                               int* __restrict__ ssrc, int E) {
    int e = blockIdx.x * blockDim.x + threadIdx.x;
    if (e >= E) return;
    int d = dst[e];
    int pos = offsets[d] + atomicAdd(&cursor[d], 1);
    ssrc[pos] = src[e];
}

// ---------------- transform: tiled f32 GEMM ----------------
// Wp[k*HF + hd*F + f] = W[hd, k, f]
__global__ void repack_w(const float* __restrict__ W, float* __restrict__ Wp, int FIN, int F) {
    int HF = HHEADS * F;
    int i = blockIdx.x * blockDim.x + threadIdx.x;
    if (i >= FIN * HF) return;
    int k = i / HF, c = i % HF;
    int hd = c / F, f = c % F;
    Wp[i] = W[(hd * FIN + k) * F + f];
}

// C[M,N] = A[M,K] @ B[K,N].  BM=BN=64, BK=32, 256 threads, 4x4 micro-tile.
template <int BM, int BN, int BK>
__global__ __launch_bounds__(256) void gemm_kernel(const float* __restrict__ A,
                                                   const float* __restrict__ B,
                                                   float* __restrict__ C, int M, int K, int N) {
    __shared__ float As[BK][BM + 4];
    __shared__ float Bs[BK][BN];
    int tid = threadIdx.x;
    int tx = tid % 16, ty = tid / 16;
    int m0 = blockIdx.y * BM, n0 = blockIdx.x * BN;
    float acc[4][4] = {};
    for (int kk0 = 0; kk0 < K; kk0 += BK) {
#pragma unroll
        for (int i = 0; i < (BM * BK) / 256; ++i) {
            int idx = tid + i * 256;
            int m = idx / BK, k = idx % BK;
            float v = 0.f;
            if (m0 + m < M && kk0 + k < K) v = A[(size_t)(m0 + m) * K + kk0 + k];
            As[k][m] = v;
        }
#pragma unroll
        for (int i = 0; i < (BK * BN) / 1024; ++i) {
            int idx = tid + i * 256;
            int k = idx / (BN / 4), n4 = idx % (BN / 4);
            float4 v = make_float4(0.f, 0.f, 0.f, 0.f);
            if (kk0 + k < K && n0 + n4 * 4 < N)
                v = *(const float4*)&B[(size_t)(kk0 + k) * N + n0 + n4 * 4];
            *(float4*)&Bs[k][n4 * 4] = v;
        }
        __syncthreads();
#pragma unroll
        for (int k = 0; k < BK; ++k) {
            float4 av = *(const float4*)&As[k][ty * 4];
            float4 bv = *(const float4*)&Bs[k][tx * 4];
            float a[4] = {av.x, av.y, av.z, av.w};
            float b[4] = {bv.x, bv.y, bv.z, bv.w};
#pragma unroll
            for (int i = 0; i < 4; ++i)
#pragma unroll
                for (int j = 0; j < 4; ++j) acc[i][j] += a[i] * b[j];
        }
        __syncthreads();
    }
#pragma unroll
    for (int i = 0; i < 4; ++i) {
        int m = m0 + ty * 4 + i;
        if (m < M && n0 + tx * 4 < N) {
            float4 v = make_float4(acc[i][0], acc[i][1], acc[i][2], acc[i][3]);
            *(float4*)&C[(size_t)m * N + n0 + tx * 4] = v;
        }
    }
}

// es[n,hd] = sum_f h[n,hd,f]*a_s[hd,f]; block = HF threads, one node per block.
template <int F>
__global__ void attn_terms(const float* __restrict__ h, const float* __restrict__ as_,
                           const float* __restrict__ ad_, float* __restrict__ es,
                           float* __restrict__ ed) {
    constexpr int HF = HHEADS * F;
    int node = blockIdx.x;
    int t = threadIdx.x;
    float v = h[(size_t)node * HF + t];
    float s = v * as_[t];
    float d = v * ad_[t];
#pragma unroll
    for (int off = F / 2; off > 0; off >>= 1) {
        s += __shfl_down(s, off, F);
        d += __shfl_down(d, off, F);
    }
    if ((t & (F - 1)) == 0) {
        int hd = t / F;
        es[node * HHEADS + hd] = s;
        ed[node * HHEADS + hd] = d;
    }
}

// ---------------- edge softmax: dst-centric, atomic-free ----------------
// thread per (node, head). alpha written in CSR order (unnormalized exp);
// denom[node*H+hd] = sum. es gathers are L2-resident (1.2 MB).
__global__ void edge_softmax(const float* __restrict__ es, const float* __restrict__ ed,
                             const int* __restrict__ offsets, const int* __restrict__ ssrc,
                             float* __restrict__ alpha, float* __restrict__ denom, int n) {
    int i = blockIdx.x * blockDim.x + threadIdx.x;
    if (i >= n * HHEADS) return;
    int node = i / HHEADS, hd = i % HHEADS;
    int a = offsets[node], b = offsets[node + 1];
    float edv = ed[i];
    float m = -1e30f;
    for (int j = a; j < b; ++j) {
        float v = es[ssrc[j] * HHEADS + hd] + edv;
        v = v > 0.f ? v : 0.2f * v;  // leaky relu 0.2
        m = fmaxf(m, v);
    }
    float sum = 0.f;
    for (int j = a; j < b; ++j) {
        float v = es[ssrc[j] * HHEADS + hd] + edv;
        v = v > 0.f ? v : 0.2f * v;
        float ex = expf(v - m);
        alpha[(size_t)j * HHEADS + hd] = ex;
        sum += ex;
    }
    denom[i] = sum;
}

// thread per (node, 4-channel group); float4 gathers of h[src], alpha read in
// CSR order, atomic-free.
template <int F>
__global__ void aggregate_kernel(const float* __restrict__ h, const float* __restrict__ alpha,
                                 const float* __restrict__ denom,
                                 const int* __restrict__ offsets, const int* __restrict__ ssrc,
                                 float* __restrict__ out, int n) {
    constexpr int HF = HHEADS * F;
    constexpr int C4 = HF / 4;
    int tid = blockIdx.x * blockDim.x + threadIdx.x;
    if (tid >= n * C4) return;
    int node = tid / C4, q = tid % C4;
    int c = q * 4, hd = c / F;
    int a = offsets[node], b = offsets[node + 1];
    float4 acc = make_float4(0.f, 0.f, 0.f, 0.f);
    for (int j = a; j < b; ++j) {
        int s = ssrc[j];
        float al = alpha[(size_t)j * HHEADS + hd];
        float4 hv = *(const float4*)&h[(size_t)s * HF + c];
        acc.x += al * hv.x;
        acc.y += al * hv.y;
        acc.z += al * hv.z;
        acc.w += al * hv.w;
    }
    float invd = 1.0f / (denom[node * HHEADS + hd] + 1e-16f);
    acc.x *= invd;
    acc.y *= invd;
    acc.z *= invd;
    acc.w *= invd;
    acc.x = acc.x > 0.f ? acc.x : (expf(acc.x) - 1.0f);  // elu
    acc.y = acc.y > 0.f ? acc.y : (expf(acc.y) - 1.0f);
    acc.z = acc.z > 0.f ? acc.z : (expf(acc.z) - 1.0f);
    acc.w = acc.w > 0.f ? acc.w : (expf(acc.w) - 1.0f);
    *(float4*)&out[(size_t)node * HF + c] = acc;
}

// ---------------- pooling + head ----------------
__global__ void pool_kernel(const float* __restrict__ out3, float* __restrict__ g, int n) {
    int b = blockIdx.x, t = threadIdx.x;
    int chunk = (n + gridDim.x - 1) / gridDim.x;
    int n0 = b * chunk, n1 = min(n, n0 + chunk);
    float a0 = 0.f, a1 = 0.f;
    for (int node = n0; node < n1; ++node) {
        a0 += out3[(size_t)node * 384 + t];
        if (t < 128) a1 += out3[(size_t)node * 384 + 256 + t];
    }
    atomicAdd(&g[t], a0);
    if (t < 128) atomicAdd(&g[256 + t], a1);
}

__global__ void final_kernel(const float* __restrict__ g, const float* __restrict__ Wd,
                             const float* __restrict__ bd, float* __restrict__ outp) {
    __shared__ float red[384];
    int t = threadIdx.x;  // blockDim = 384
    float v = g[t];
    red[t] = v * v;
    __syncthreads();
    for (int s = 192; s >= 3; s >>= 1) {
        if (t < s) red[t] += red[t + s];
        __syncthreads();
    }
    __shared__ float scale_s;
    if (t == 0) {
        float norm = sqrtf(red[0] + red[1] + red[2]);
        scale_s = 1.0f / fmaxf(norm, 1e-12f);
    }
    __syncthreads();
    float scale = scale_s;
    red[t] = v * scale * Wd[t];
    __syncthreads();
    for (int s = 192; s >= 3; s >>= 1) {
        if (t < s) red[t] += red[t + s];
        __syncthreads();
    }
    if (t == 0) outp[0] = red[0] + red[1] + red[2] + bd[0];
}

// ---------------- host side ----------------
template <int FIN, int F>
static void run_layer(const float* xin, const float* W, const float* as_, const float* ad_,
                      float* wp, float* hbuf, float* outbuf, float* es, float* ed,
                      float* denom, float* alpha, const int* src, const int* dst,
                      const int* offsets, const int* ssrc, int N, int E, hipStream_t stream) {
    constexpr int HF = HHEADS * F;
    repack_w<<<(FIN * HF + 255) / 256, 256, 0, stream>>>(W, wp, FIN, F);
    dim3 grid((HF + 63) / 64, (N + 63) / 64);
    gemm_kernel<64, 64, 32><<<grid, 256, 0, stream>>>(xin, wp, hbuf, N, FIN, HF);
    attn_terms<F><<<N, HF, 0, stream>>>(hbuf, as_, ad_, es, ed);
    edge_softmax<<<(N * HHEADS + 255) / 256, 256, 0, stream>>>(es, ed, offsets, ssrc, alpha,
                                                               denom, N);
    long total = (long)N * HF / 4;
    aggregate_kernel<F><<<(total + 255) / 256, 256, 0, stream>>>(hbuf, alpha, denom, offsets,
                                                                 ssrc, outbuf, N);
}

extern "C" void kernel_launch(void* const* d_in, const int* in_sizes, int n_in, void* d_out,
                              int out_size, void* d_ws, size_t ws_size, hipStream_t stream) {
    const float* x = (const float*)d_in[0];
    const int* ei = (const int*)d_in[1];
    const float* W1 = (const float*)d_in[2];
    const float* a1s = (const float*)d_in[3];
    const float* a1d = (const float*)d_in[4];
    const float* W2 = (const float*)d_in[5];
    const float* a2s = (const float*)d_in[6];
    const float* a2d = (const float*)d_in[7];
    const float* W3 = (const float*)d_in[8];
    const float* a3s = (const float*)d_in[9];
    const float* a3d = (const float*)d_in[10];
    const float* Wd = (const float*)d_in[11];
    const float* bd = (const float*)d_in[12];
    float* outp = (float*)d_out;

    const int N = in_sizes[0] / 11;
    const int E = in_sizes[1] / 2;
    const int* src = ei;
    const int* dst = ei + E;

    char* w = (char*)d_ws;
    size_t off = 0;
    auto A = [&](size_t bytes) {
        size_t o = off;
        off += (bytes + 255) & ~(size_t)255;
        return o;
    };
    float* bufH = (float*)(w + A((size_t)N * 384 * 4));
    float* bufA = (float*)(w + A((size_t)N * 384 * 4));  // layer1 out (96), layer3 out (384)
    float* bufB = (float*)(w + A((size_t)N * 192 * 4));  // layer2 out
    float* es = (float*)(w + A((size_t)N * HHEADS * 4));
    float* ed = (float*)(w + A((size_t)N * HHEADS * 4));
    float* denom = (float*)(w + A((size_t)N * HHEADS * 4));
    float* alpha = (float*)(w + A((size_t)E * HHEADS * 4));
    float* wp = (float*)(w + A((size_t)192 * 384 * 4));  // repacked W, max layer3
    int* count = (int*)(w + A((size_t)(N + 1) * 4));
    int* cursor = (int*)(w + A((size_t)(N + 1) * 4));
    int* offsets = (int*)(w + A((size_t)(N + 1) * 4));
    int* ssrc = (int*)(w + A((size_t)E * 4));
    float* g = (float*)(w + A(384 * 4));

    // CSR build (by dst)
    hipMemsetAsync(count, 0, (size_t)N * 4, stream);
    hipMemsetAsync(cursor, 0, (size_t)N * 4, stream);
    hist_kernel<<<(E + 255) / 256, 256, 0, stream>>>(dst, count, E);
    scan_kernel<<<1, 1024, 0, stream>>>(count, offsets, N, E);
    scatter_kernel<<<(E + 255) / 256, 256, 0, stream>>>(src, dst, offsets, cursor, ssrc, E);

    // 3 GAT layers
    run_layer<11, 16>(x, W1, a1s, a1d, wp, bufH, bufA, es, ed, denom, alpha, src, dst, offsets,
                      ssrc, N, E, stream);
    run_layer<96, 32>(bufA, W2, a2s, a2d, wp, bufH, bufB, es, ed, denom, alpha, src, dst,
                      offsets, ssrc, N, E, stream);
    run_layer<192, 64>(bufB, W3, a3s, a3d, wp, bufH, bufA, es, ed, denom, alpha, src, dst,
                       offsets, ssrc, N, E, stream);

    // sum-pool -> normalize -> dense
    hipMemsetAsync(g, 0, 384 * 4, stream);
    pool_kernel<<<256, 256, 0, stream>>>(bufA, g, N);
    final_kernel<<<1, 384, 0, stream>>>(g, Wd, bd, outp);
}

// Round 4
// 835.461 us; speedup vs baseline: 3.7889x; 1.1598x over previous
//
#include <hip/hip_runtime.h>
#include <hip/hip_bf16.h>

// GAT 3-layer: N=50000 nodes, E=800000 edges, H=6 heads.
// CSR-by-dst built per call; dst-centric atomic-free aggregation.
// R1: transforms = tiled f32 GEMMs (W re-read was L2-BW bound at 577us).
// R2: dst-centric edge softmax over CSR (zero atomics), alpha in CSR order.
// R3: h stored bf16 (gather volume halves: aggregate was fetch-BW bound at
//     592 MB/dispatch); f32 accumulate everywhere, outputs stay f32.

#define HHEADS 6

__device__ __forceinline__ float bfl(unsigned u) {  // low bf16 of a uint -> f32
    return __uint_as_float(u << 16);
}
__device__ __forceinline__ float bfh(unsigned u) {  // high bf16 of a uint -> f32
    return __uint_as_float(u & 0xffff0000u);
}

// ---------------- CSR build ----------------
__global__ void hist_kernel(const int* __restrict__ dst, int* __restrict__ count, int E) {
    int e = blockIdx.x * blockDim.x + threadIdx.x;
    if (e >= E) return;
    atomicAdd(&count[dst[e]], 1);
}

__global__ void scan_kernel(const int* __restrict__ count, int* __restrict__ offsets,
                            int n, int total) {
    __shared__ int sdata[1024];
    __shared__ int sbase;
    if (threadIdx.x == 0) sbase = 0;
    __syncthreads();
    int nchunks = (n + 1023) / 1024;
    for (int ch = 0; ch < nchunks; ++ch) {
        int i = ch * 1024 + threadIdx.x;
        int v = (i < n) ? count[i] : 0;
        int base = sbase;
        sdata[threadIdx.x] = v;
        __syncthreads();
        for (int off = 1; off < 1024; off <<= 1) {
            int tmp = (threadIdx.x >= (unsigned)off) ? sdata[threadIdx.x - off] : 0;
            __syncthreads();
            sdata[threadIdx.x] += tmp;
            __syncthreads();
        }
        int incl = sdata[threadIdx.x];
        if (i < n) offsets[i] = base + (incl - v);
        __syncthreads();
        if (threadIdx.x == 1023) sbase = base + sdata[1023];
        __syncthreads();
    }
    if (threadIdx.x == 0) offsets[n] = total;
}

__global__ void scatter_kernel(const int* __restrict__ src, const int* __restrict__ dst,
                               const int* __restrict__ offsets, int* __restrict__ cursor,
                               int* __restrict__ ssrc, int E) {
    int e = blockIdx.x * blockDim.x + threadIdx.x;
    if (e >= E) return;
    int d = dst[e];
    int pos = offsets[d] + atomicAdd(&cursor[d], 1);
    ssrc[pos] = src[e];
}

// ---------------- transform: tiled f32 GEMM, bf16 output ----------------
// Wp[k*HF + hd*F + f] = W[hd, k, f]
__global__ void repack_w(const float* __restrict__ W, float* __restrict__ Wp, int FIN, int F) {
    int HF = HHEADS * F;
    int i = blockIdx.x * blockDim.x + threadIdx.x;
    if (i >= FIN * HF) return;
    int k = i / HF, c = i % HF;
    int hd = c / F, f = c % F;
    Wp[i] = W[(hd * FIN + k) * F + f];
}

// C[M,N] = A[M,K] @ B[K,N], C written as bf16. BM=BN=64, BK=32, 256 thr, 4x4.
template <int BM, int BN, int BK>
__global__ __launch_bounds__(256) void gemm_kernel(const float* __restrict__ A,
                                                   const float* __restrict__ B,
                                                   __hip_bfloat16* __restrict__ C, int M,
                                                   int K, int N) {
    __shared__ float As[BK][BM + 4];
    __shared__ float Bs[BK][BN];
    int tid = threadIdx.x;
    int tx = tid % 16, ty = tid / 16;
    int m0 = blockIdx.y * BM, n0 = blockIdx.x * BN;
    float acc[4][4] = {};
    for (int kk0 = 0; kk0 < K; kk0 += BK) {
#pragma unroll
        for (int i = 0; i < (BM * BK) / 256; ++i) {
            int idx = tid + i * 256;
            int m = idx / BK, k = idx % BK;
            float v = 0.f;
            if (m0 + m < M && kk0 + k < K) v = A[(size_t)(m0 + m) * K + kk0 + k];
            As[k][m] = v;
        }
#pragma unroll
        for (int i = 0; i < (BK * BN) / 1024; ++i) {
            int idx = tid + i * 256;
            int k = idx / (BN / 4), n4 = idx % (BN / 4);
            float4 v = make_float4(0.f, 0.f, 0.f, 0.f);
            if (kk0 + k < K && n0 + n4 * 4 < N)
                v = *(const float4*)&B[(size_t)(kk0 + k) * N + n0 + n4 * 4];
            *(float4*)&Bs[k][n4 * 4] = v;
        }
        __syncthreads();
#pragma unroll
        for (int k = 0; k < BK; ++k) {
            float4 av = *(const float4*)&As[k][ty * 4];
            float4 bv = *(const float4*)&Bs[k][tx * 4];
            float a[4] = {av.x, av.y, av.z, av.w};
            float b[4] = {bv.x, bv.y, bv.z, bv.w};
#pragma unroll
            for (int i = 0; i < 4; ++i)
#pragma unroll
                for (int j = 0; j < 4; ++j) acc[i][j] += a[i] * b[j];
        }
        __syncthreads();
    }
#pragma unroll
    for (int i = 0; i < 4; ++i) {
        int m = m0 + ty * 4 + i;
        if (m < M && n0 + tx * 4 < N) {
            __hip_bfloat16 tmp[4];
#pragma unroll
            for (int j = 0; j < 4; ++j) tmp[j] = __float2bfloat16(acc[i][j]);
            *(uint2*)&C[(size_t)m * N + n0 + tx * 4] = *(uint2*)tmp;
        }
    }
}

// es[n,hd] = sum_f h[n,hd,f]*a_s[hd,f]; block = HF threads, one node per block.
template <int F>
__global__ void attn_terms(const __hip_bfloat16* __restrict__ h, const float* __restrict__ as_,
                           const float* __restrict__ ad_, float* __restrict__ es,
                           float* __restrict__ ed) {
    constexpr int HF = HHEADS * F;
    int node = blockIdx.x;
    int t = threadIdx.x;
    float v = __bfloat162float(h[(size_t)node * HF + t]);
    float s = v * as_[t];
    float d = v * ad_[t];
#pragma unroll
    for (int off = F / 2; off > 0; off >>= 1) {
        s += __shfl_down(s, off, F);
        d += __shfl_down(d, off, F);
    }
    if ((t & (F - 1)) == 0) {
        int hd = t / F;
        es[node * HHEADS + hd] = s;
        ed[node * HHEADS + hd] = d;
    }
}

// ---------------- edge softmax: dst-centric, atomic-free ----------------
__global__ void edge_softmax(const float* __restrict__ es, const float* __restrict__ ed,
                             const int* __restrict__ offsets, const int* __restrict__ ssrc,
                             float* __restrict__ alpha, float* __restrict__ denom, int n) {
    int i = blockIdx.x * blockDim.x + threadIdx.x;
    if (i >= n * HHEADS) return;
    int node = i / HHEADS, hd = i % HHEADS;
    int a = offsets[node], b = offsets[node + 1];
    float edv = ed[i];
    float m = -1e30f;
    for (int j = a; j < b; ++j) {
        float v = es[ssrc[j] * HHEADS + hd] + edv;
        v = v > 0.f ? v : 0.2f * v;  // leaky relu 0.2
        m = fmaxf(m, v);
    }
    float sum = 0.f;
    for (int j = a; j < b; ++j) {
        float v = es[ssrc[j] * HHEADS + hd] + edv;
        v = v > 0.f ? v : 0.2f * v;
        float ex = expf(v - m);
        alpha[(size_t)j * HHEADS + hd] = ex;
        sum += ex;
    }
    denom[i] = sum;
}

// thread per (node, 8-channel group); 16B uint4 gathers of bf16 h[src].
template <int F>
__global__ void aggregate_kernel(const __hip_bfloat16* __restrict__ h,
                                 const float* __restrict__ alpha,
                                 const float* __restrict__ denom,
                                 const int* __restrict__ offsets, const int* __restrict__ ssrc,
                                 float* __restrict__ out, int n) {
    constexpr int HF = HHEADS * F;
    constexpr int C8 = HF / 8;
    int tid = blockIdx.x * blockDim.x + threadIdx.x;
    if (tid >= n * C8) return;
    int node = tid / C8, q = tid % C8;
    int c = q * 8, hd = c / F;
    int a = offsets[node], b = offsets[node + 1];
    float acc[8] = {};
    for (int j = a; j < b; ++j) {
        int s = ssrc[j];
        float al = alpha[(size_t)j * HHEADS + hd];
        uint4 hv = *(const uint4*)&h[(size_t)s * HF + c];
        acc[0] += al * bfl(hv.x);
        acc[1] += al * bfh(hv.x);
        acc[2] += al * bfl(hv.y);
        acc[3] += al * bfh(hv.y);
        acc[4] += al * bfl(hv.z);
        acc[5] += al * bfh(hv.z);
        acc[6] += al * bfl(hv.w);
        acc[7] += al * bfh(hv.w);
    }
    float invd = 1.0f / (denom[node * HHEADS + hd] + 1e-16f);
    float4 o0, o1;
    float* op = &o0.x;
#pragma unroll
    for (int k = 0; k < 8; ++k) {
        float v = acc[k] * invd;
        v = v > 0.f ? v : (expf(v) - 1.0f);  // elu
        op[k] = v;
    }
    *(float4*)&out[(size_t)node * HF + c] = o0;
    *(float4*)&out[(size_t)node * HF + c + 4] = o1;
}

// ---------------- pooling + head ----------------
__global__ void pool_kernel(const float* __restrict__ out3, float* __restrict__ g, int n) {
    int b = blockIdx.x, t = threadIdx.x;
    int chunk = (n + gridDim.x - 1) / gridDim.x;
    int n0 = b * chunk, n1 = min(n, n0 + chunk);
    float a0 = 0.f, a1 = 0.f;
    for (int node = n0; node < n1; ++node) {
        a0 += out3[(size_t)node * 384 + t];
        if (t < 128) a1 += out3[(size_t)node * 384 + 256 + t];
    }
    atomicAdd(&g[t], a0);
    if (t < 128) atomicAdd(&g[256 + t], a1);
}

__global__ void final_kernel(const float* __restrict__ g, const float* __restrict__ Wd,
                             const float* __restrict__ bd, float* __restrict__ outp) {
    __shared__ float red[384];
    int t = threadIdx.x;  // blockDim = 384
    float v = g[t];
    red[t] = v * v;
    __syncthreads();
    for (int s = 192; s >= 3; s >>= 1) {
        if (t < s) red[t] += red[t + s];
        __syncthreads();
    }
    __shared__ float scale_s;
    if (t == 0) {
        float norm = sqrtf(red[0] + red[1] + red[2]);
        scale_s = 1.0f / fmaxf(norm, 1e-12f);
    }
    __syncthreads();
    float scale = scale_s;
    red[t] = v * scale * Wd[t];
    __syncthreads();
    for (int s = 192; s >= 3; s >>= 1) {
        if (t < s) red[t] += red[t + s];
        __syncthreads();
    }
    if (t == 0) outp[0] = red[0] + red[1] + red[2] + bd[0];
}

// ---------------- host side ----------------
template <int FIN, int F>
static void run_layer(const float* xin, const float* W, const float* as_, const float* ad_,
                      float* wp, __hip_bfloat16* hbuf, float* outbuf, float* es, float* ed,
                      float* denom, float* alpha, const int* src, const int* dst,
                      const int* offsets, const int* ssrc, int N, int E, hipStream_t stream) {
    constexpr int HF = HHEADS * F;
    repack_w<<<(FIN * HF + 255) / 256, 256, 0, stream>>>(W, wp, FIN, F);
    dim3 grid((HF + 63) / 64, (N + 63) / 64);
    gemm_kernel<64, 64, 32><<<grid, 256, 0, stream>>>(xin, wp, hbuf, N, FIN, HF);
    attn_terms<F><<<N, HF, 0, stream>>>(hbuf, as_, ad_, es, ed);
    edge_softmax<<<(N * HHEADS + 255) / 256, 256, 0, stream>>>(es, ed, offsets, ssrc, alpha,
                                                               denom, N);
    long total = (long)N * HF / 8;
    aggregate_kernel<F><<<(total + 255) / 256, 256, 0, stream>>>(hbuf, alpha, denom, offsets,
                                                                 ssrc, outbuf, N);
}

extern "C" void kernel_launch(void* const* d_in, const int* in_sizes, int n_in, void* d_out,
                              int out_size, void* d_ws, size_t ws_size, hipStream_t stream) {
    const float* x = (const float*)d_in[0];
    const int* ei = (const int*)d_in[1];
    const float* W1 = (const float*)d_in[2];
    const float* a1s = (const float*)d_in[3];
    const float* a1d = (const float*)d_in[4];
    const float* W2 = (const float*)d_in[5];
    const float* a2s = (const float*)d_in[6];
    const float* a2d = (const float*)d_in[7];
    const float* W3 = (const float*)d_in[8];
    const float* a3s = (const float*)d_in[9];
    const float* a3d = (const float*)d_in[10];
    const float* Wd = (const float*)d_in[11];
    const float* bd = (const float*)d_in[12];
    float* outp = (float*)d_out;

    const int N = in_sizes[0] / 11;
    const int E = in_sizes[1] / 2;
    const int* src = ei;
    const int* dst = ei + E;

    char* w = (char*)d_ws;
    size_t off = 0;
    auto A = [&](size_t bytes) {
        size_t o = off;
        off += (bytes + 255) & ~(size_t)255;
        return o;
    };
    __hip_bfloat16* bufH = (__hip_bfloat16*)(w + A((size_t)N * 384 * 2));  // bf16 h
    float* bufA = (float*)(w + A((size_t)N * 384 * 4));  // layer1 out (96), layer3 out (384)
    float* bufB = (float*)(w + A((size_t)N * 192 * 4));  // layer2 out
    float* es = (float*)(w + A((size_t)N * HHEADS * 4));
    float* ed = (float*)(w + A((size_t)N * HHEADS * 4));
    float* denom = (float*)(w + A((size_t)N * HHEADS * 4));
    float* alpha = (float*)(w + A((size_t)E * HHEADS * 4));
    float* wp = (float*)(w + A((size_t)192 * 384 * 4));  // repacked W, max layer3
    int* count = (int*)(w + A((size_t)(N + 1) * 4));
    int* cursor = (int*)(w + A((size_t)(N + 1) * 4));
    int* offsets = (int*)(w + A((size_t)(N + 1) * 4));
    int* ssrc = (int*)(w + A((size_t)E * 4));
    float* g = (float*)(w + A(384 * 4));

    // CSR build (by dst)
    hipMemsetAsync(count, 0, (size_t)N * 4, stream);
    hipMemsetAsync(cursor, 0, (size_t)N * 4, stream);
    hist_kernel<<<(E + 255) / 256, 256, 0, stream>>>(dst, count, E);
    scan_kernel<<<1, 1024, 0, stream>>>(count, offsets, N, E);
    scatter_kernel<<<(E + 255) / 256, 256, 0, stream>>>(src, dst, offsets, cursor, ssrc, E);

    // 3 GAT layers
    run_layer<11, 16>(x, W1, a1s, a1d, wp, bufH, bufA, es, ed, denom, alpha, src, dst, offsets,
                      ssrc, N, E, stream);
    run_layer<96, 32>(bufA, W2, a2s, a2d, wp, bufH, bufB, es, ed, denom, alpha, src, dst,
                      offsets, ssrc, N, E, stream);
    run_layer<192, 64>(bufB, W3, a3s, a3d, wp, bufH, bufA, es, ed, denom, alpha, src, dst,
                       offsets, ssrc, N, E, stream);

    // sum-pool -> normalize -> dense
    hipMemsetAsync(g, 0, 384 * 4, stream);
    pool_kernel<<<256, 256, 0, stream>>>(bufA, g, N);
    final_kernel<<<1, 384, 0, stream>>>(g, Wd, bd, outp);
}

// Round 5
// 797.388 us; speedup vs baseline: 3.9698x; 1.0477x over previous
//
#include <hip/hip_runtime.h>
#include <hip/hip_bf16.h>

// GAT 3-layer: N=50000 nodes, E=800000 edges, H=6 heads.
// CSR-by-dst built per call; dst-centric atomic-free aggregation.
// R1: transforms = tiled f32 GEMMs (W re-read was L2-BW bound at 577us).
// R2: dst-centric edge softmax over CSR (zero atomics), alpha in CSR order.
// R3: h stored bf16 (aggregate was fetch-BW bound); f32 accumulate everywhere.
// R4: layers 2/3 GEMM = 128x128 tile, 8x8 split micro-tile (VALU-bound now),
//     attn es/ed fused into GEMM epilogue (segmented shfl reduce).

#define HHEADS 6

__device__ __forceinline__ float bfl(unsigned u) { return __uint_as_float(u << 16); }
__device__ __forceinline__ float bfh(unsigned u) { return __uint_as_float(u & 0xffff0000u); }

// ---------------- CSR build ----------------
__global__ void hist_kernel(const int* __restrict__ dst, int* __restrict__ count, int E) {
    int e = blockIdx.x * blockDim.x + threadIdx.x;
    if (e >= E) return;
    atomicAdd(&count[dst[e]], 1);
}

__global__ void scan_kernel(const int* __restrict__ count, int* __restrict__ offsets,
                            int n, int total) {
    __shared__ int sdata[1024];
    __shared__ int sbase;
    if (threadIdx.x == 0) sbase = 0;
    __syncthreads();
    int nchunks = (n + 1023) / 1024;
    for (int ch = 0; ch < nchunks; ++ch) {
        int i = ch * 1024 + threadIdx.x;
        int v = (i < n) ? count[i] : 0;
        int base = sbase;
        sdata[threadIdx.x] = v;
        __syncthreads();
        for (int off = 1; off < 1024; off <<= 1) {
            int tmp = (threadIdx.x >= (unsigned)off) ? sdata[threadIdx.x - off] : 0;
            __syncthreads();
            sdata[threadIdx.x] += tmp;
            __syncthreads();
        }
        int incl = sdata[threadIdx.x];
        if (i < n) offsets[i] = base + (incl - v);
        __syncthreads();
        if (threadIdx.x == 1023) sbase = base + sdata[1023];
        __syncthreads();
    }
    if (threadIdx.x == 0) offsets[n] = total;
}

__global__ void scatter_kernel(const int* __restrict__ src, const int* __restrict__ dst,
                               const int* __restrict__ offsets, int* __restrict__ cursor,
                               int* __restrict__ ssrc, int E) {
    int e = blockIdx.x * blockDim.x + threadIdx.x;
    if (e >= E) return;
    int d = dst[e];
    int pos = offsets[d] + atomicAdd(&cursor[d], 1);
    ssrc[pos] = src[e];
}

// ---------------- weight repack: Wp[k*HF + hd*F + f] = W[hd,k,f] ----------------
__global__ void repack_w(const float* __restrict__ W, float* __restrict__ Wp, int FIN, int F) {
    int HF = HHEADS * F;
    int i = blockIdx.x * blockDim.x + threadIdx.x;
    if (i >= FIN * HF) return;
    int k = i / HF, c = i % HF;
    int hd = c / F, f = c % F;
    Wp[i] = W[(hd * FIN + k) * F + f];
}

// ---------------- small GEMM (layer 1, K=11): 64x64, 4x4 micro-tile ----------------
template <int BM, int BN, int BK>
__global__ __launch_bounds__(256) void gemm_small(const float* __restrict__ A,
                                                  const float* __restrict__ B,
                                                  __hip_bfloat16* __restrict__ C, int M,
                                                  int K, int N) {
    __shared__ float As[BK][BM + 4];
    __shared__ float Bs[BK][BN];
    int tid = threadIdx.x;
    int tx = tid % 16, ty = tid / 16;
    int m0 = blockIdx.y * BM, n0 = blockIdx.x * BN;
    float acc[4][4] = {};
    for (int kk0 = 0; kk0 < K; kk0 += BK) {
#pragma unroll
        for (int i = 0; i < (BM * BK) / 256; ++i) {
            int idx = tid + i * 256;
            int m = idx / BK, k = idx % BK;
            float v = 0.f;
            if (m0 + m < M && kk0 + k < K) v = A[(size_t)(m0 + m) * K + kk0 + k];
            As[k][m] = v;
        }
#pragma unroll
        for (int i = 0; i < (BK * BN) / 1024; ++i) {
            int idx = tid + i * 256;
            int k = idx / (BN / 4), n4 = idx % (BN / 4);
            float4 v = make_float4(0.f, 0.f, 0.f, 0.f);
            if (kk0 + k < K && n0 + n4 * 4 < N)
                v = *(const float4*)&B[(size_t)(kk0 + k) * N + n0 + n4 * 4];
            *(float4*)&Bs[k][n4 * 4] = v;
        }
        __syncthreads();
#pragma unroll
        for (int k = 0; k < BK; ++k) {
            float4 av = *(const float4*)&As[k][ty * 4];
            float4 bv = *(const float4*)&Bs[k][tx * 4];
            float a[4] = {av.x, av.y, av.z, av.w};
            float b[4] = {bv.x, bv.y, bv.z, bv.w};
#pragma unroll
            for (int i = 0; i < 4; ++i)
#pragma unroll
                for (int j = 0; j < 4; ++j) acc[i][j] += a[i] * b[j];
        }
        __syncthreads();
    }
#pragma unroll
    for (int i = 0; i < 4; ++i) {
        int m = m0 + ty * 4 + i;
        if (m < M && n0 + tx * 4 < N) {
            __hip_bfloat16 tmp[4];
#pragma unroll
            for (int j = 0; j < 4; ++j) tmp[j] = __float2bfloat16(acc[i][j]);
            *(uint2*)&C[(size_t)m * N + n0 + tx * 4] = *(uint2*)tmp;
        }
    }
}

// es[n,hd] for layer 1; block = HF threads, one node per block.
template <int F>
__global__ void attn_terms(const __hip_bfloat16* __restrict__ h, const float* __restrict__ as_,
                           const float* __restrict__ ad_, float* __restrict__ es,
                           float* __restrict__ ed) {
    constexpr int HF = HHEADS * F;
    int node = blockIdx.x;
    int t = threadIdx.x;
    float v = __bfloat162float(h[(size_t)node * HF + t]);
    float s = v * as_[t];
    float d = v * ad_[t];
#pragma unroll
    for (int off = F / 2; off > 0; off >>= 1) {
        s += __shfl_down(s, off, F);
        d += __shfl_down(d, off, F);
    }
    if ((t & (F - 1)) == 0) {
        int hd = t / F;
        es[node * HHEADS + hd] = s;
        ed[node * HHEADS + hd] = d;
    }
}

// ---------------- big GEMM + fused attn (layers 2/3) ----------------
// C[M,N] = A[M,K] @ B[K,N], C bf16; es/ed computed from f32 acc in epilogue.
// BM=BN=128, BK=16, 256 threads, 8x8 micro-tile as 2x2 split 4x4 blocks.
// Requires: K % 16 == 0, N % 64 == 0, F in {32,64}.
template <int F>
__global__ __launch_bounds__(256) void gemm_attn(const float* __restrict__ A,
                                                 const float* __restrict__ B,
                                                 __hip_bfloat16* __restrict__ C,
                                                 const float* __restrict__ as_,
                                                 const float* __restrict__ ad_,
                                                 float* __restrict__ es, float* __restrict__ ed,
                                                 int M, int K, int N) {
    constexpr int BM = 128, BN = 128, BK = 16;
    __shared__ float As[BK][BM + 4];  // stride 132: staging writes 2-way (free)
    __shared__ float Bs[BK][BN];
    int tid = threadIdx.x;
    int tx = tid % 16, ty = tid / 16;
    int m0 = blockIdx.y * BM, n0 = blockIdx.x * BN;
    float acc[2][2][4][4] = {};  // [ri][ci][i][j]
    for (int kk0 = 0; kk0 < K; kk0 += BK) {
        // stage A: 128 rows x 16 k = 512 float4 (K%16==0 -> no k guard)
#pragma unroll
        for (int i = 0; i < 2; ++i) {
            int idx = tid + i * 256;
            int m = idx >> 2, k4 = idx & 3;
            int gm = m0 + m;
            float4 v = make_float4(0.f, 0.f, 0.f, 0.f);
            if (gm < M) v = *(const float4*)&A[(size_t)gm * K + kk0 + k4 * 4];
            As[k4 * 4 + 0][m] = v.x;
            As[k4 * 4 + 1][m] = v.y;
            As[k4 * 4 + 2][m] = v.z;
            As[k4 * 4 + 3][m] = v.w;
        }
        // stage B: 16 k x 128 cols = 512 float4
#pragma unroll
        for (int i = 0; i < 2; ++i) {
            int idx = tid + i * 256;
            int k = idx >> 5, n4 = idx & 31;
            float4 v = make_float4(0.f, 0.f, 0.f, 0.f);
            if (n0 + n4 * 4 < N) v = *(const float4*)&B[(size_t)(kk0 + k) * N + n0 + n4 * 4];
            *(float4*)&Bs[k][n4 * 4] = v;
        }
        __syncthreads();
#pragma unroll
        for (int k = 0; k < BK; ++k) {
            float4 a0 = *(const float4*)&As[k][ty * 4];
            float4 a1 = *(const float4*)&As[k][64 + ty * 4];
            float4 b0 = *(const float4*)&Bs[k][tx * 4];
            float4 b1 = *(const float4*)&Bs[k][64 + tx * 4];
            float a[2][4] = {{a0.x, a0.y, a0.z, a0.w}, {a1.x, a1.y, a1.z, a1.w}};
            float b[2][4] = {{b0.x, b0.y, b0.z, b0.w}, {b1.x, b1.y, b1.z, b1.w}};
#pragma unroll
            for (int ri = 0; ri < 2; ++ri)
#pragma unroll
                for (int ci = 0; ci < 2; ++ci)
#pragma unroll
                    for (int i = 0; i < 4; ++i)
#pragma unroll
                        for (int j = 0; j < 4; ++j) acc[ri][ci][i][j] += a[ri][i] * b[ci][j];
        }
        __syncthreads();
    }
    // attention vectors for this thread's 8 columns
    float asv[2][4], adv[2][4];
#pragma unroll
    for (int ci = 0; ci < 2; ++ci)
#pragma unroll
        for (int j = 0; j < 4; ++j) {
            int c = n0 + ci * 64 + tx * 4 + j;
            asv[ci][j] = (c < N) ? as_[c] : 0.f;
            adv[ci][j] = (c < N) ? ad_[c] : 0.f;
        }
    constexpr int W = F / 4;  // lanes per head segment (8 or 16); 16 % W == 0
#pragma unroll
    for (int ri = 0; ri < 2; ++ri)
#pragma unroll
        for (int i = 0; i < 4; ++i) {
            int gm = m0 + ri * 64 + ty * 4 + i;
            bool rowok = gm < M;
#pragma unroll
            for (int ci = 0; ci < 2; ++ci) {
                int c0 = n0 + ci * 64 + tx * 4;
                if (c0 < N) {  // uniform per ci (N % 64 == 0)
                    if (rowok) {
                        __hip_bfloat16 tmp[4];
#pragma unroll
                        for (int j = 0; j < 4; ++j) tmp[j] = __float2bfloat16(acc[ri][ci][i][j]);
                        *(uint2*)&C[(size_t)gm * N + c0] = *(uint2*)tmp;
                    }
                    float ps = 0.f, pd = 0.f;
#pragma unroll
                    for (int j = 0; j < 4; ++j) {
                        ps += acc[ri][ci][i][j] * asv[ci][j];
                        pd += acc[ri][ci][i][j] * adv[ci][j];
                    }
#pragma unroll
                    for (int off = W / 2; off > 0; off >>= 1) {
                        ps += __shfl_down(ps, off, W);
                        pd += __shfl_down(pd, off, W);
                    }
                    if (rowok && (tx & (W - 1)) == 0) {
                        int hd = c0 / F;
                        es[(size_t)gm * HHEADS + hd] = ps;
                        ed[(size_t)gm * HHEADS + hd] = pd;
                    }
                }
            }
        }
}

// ---------------- edge softmax: dst-centric, atomic-free ----------------
__global__ void edge_softmax(const float* __restrict__ es, const float* __restrict__ ed,
                             const int* __restrict__ offsets, const int* __restrict__ ssrc,
                             float* __restrict__ alpha, float* __restrict__ denom, int n) {
    int i = blockIdx.x * blockDim.x + threadIdx.x;
    if (i >= n * HHEADS) return;
    int node = i / HHEADS, hd = i % HHEADS;
    int a = offsets[node], b = offsets[node + 1];
    float edv = ed[i];
    float m = -1e30f;
    for (int j = a; j < b; ++j) {
        float v = es[ssrc[j] * HHEADS + hd] + edv;
        v = v > 0.f ? v : 0.2f * v;  // leaky relu 0.2
        m = fmaxf(m, v);
    }
    float sum = 0.f;
    for (int j = a; j < b; ++j) {
        float v = es[ssrc[j] * HHEADS + hd] + edv;
        v = v > 0.f ? v : 0.2f * v;
        float ex = expf(v - m);
        alpha[(size_t)j * HHEADS + hd] = ex;
        sum += ex;
    }
    denom[i] = sum;
}

// thread per (node, 8-channel group); 16B uint4 gathers of bf16 h[src].
template <int F>
__global__ void aggregate_kernel(const __hip_bfloat16* __restrict__ h,
                                 const float* __restrict__ alpha,
                                 const float* __restrict__ denom,
                                 const int* __restrict__ offsets, const int* __restrict__ ssrc,
                                 float* __restrict__ out, int n) {
    constexpr int HF = HHEADS * F;
    constexpr int C8 = HF / 8;
    int tid = blockIdx.x * blockDim.x + threadIdx.x;
    if (tid >= n * C8) return;
    int node = tid / C8, q = tid % C8;
    int c = q * 8, hd = c / F;
    int a = offsets[node], b = offsets[node + 1];
    float acc[8] = {};
    for (int j = a; j < b; ++j) {
        int s = ssrc[j];
        float al = alpha[(size_t)j * HHEADS + hd];
        uint4 hv = *(const uint4*)&h[(size_t)s * HF + c];
        acc[0] += al * bfl(hv.x);
        acc[1] += al * bfh(hv.x);
        acc[2] += al * bfl(hv.y);
        acc[3] += al * bfh(hv.y);
        acc[4] += al * bfl(hv.z);
        acc[5] += al * bfh(hv.z);
        acc[6] += al * bfl(hv.w);
        acc[7] += al * bfh(hv.w);
    }
    float invd = 1.0f / (denom[node * HHEADS + hd] + 1e-16f);
    float4 o0, o1;
    float* op = &o0.x;
#pragma unroll
    for (int k = 0; k < 8; ++k) {
        float v = acc[k] * invd;
        v = v > 0.f ? v : (expf(v) - 1.0f);  // elu
        op[k] = v;
    }
    *(float4*)&out[(size_t)node * HF + c] = o0;
    *(float4*)&out[(size_t)node * HF + c + 4] = o1;
}

// ---------------- pooling + head ----------------
__global__ void pool_kernel(const float* __restrict__ out3, float* __restrict__ g, int n) {
    int b = blockIdx.x, t = threadIdx.x;
    int chunk = (n + gridDim.x - 1) / gridDim.x;
    int n0 = b * chunk, n1 = min(n, n0 + chunk);
    float a0 = 0.f, a1 = 0.f;
    for (int node = n0; node < n1; ++node) {
        a0 += out3[(size_t)node * 384 + t];
        if (t < 128) a1 += out3[(size_t)node * 384 + 256 + t];
    }
    atomicAdd(&g[t], a0);
    if (t < 128) atomicAdd(&g[256 + t], a1);
}

__global__ void final_kernel(const float* __restrict__ g, const float* __restrict__ Wd,
                             const float* __restrict__ bd, float* __restrict__ outp) {
    __shared__ float red[384];
    int t = threadIdx.x;  // blockDim = 384
    float v = g[t];
    red[t] = v * v;
    __syncthreads();
    for (int s = 192; s >= 3; s >>= 1) {
        if (t < s) red[t] += red[t + s];
        __syncthreads();
    }
    __shared__ float scale_s;
    if (t == 0) {
        float norm = sqrtf(red[0] + red[1] + red[2]);
        scale_s = 1.0f / fmaxf(norm, 1e-12f);
    }
    __syncthreads();
    float scale = scale_s;
    red[t] = v * scale * Wd[t];
    __syncthreads();
    for (int s = 192; s >= 3; s >>= 1) {
        if (t < s) red[t] += red[t + s];
        __syncthreads();
    }
    if (t == 0) outp[0] = red[0] + red[1] + red[2] + bd[0];
}

// ---------------- host side ----------------
template <int F>
static void run_edges_and_agg(__hip_bfloat16* hbuf, float* outbuf, float* es, float* ed,
                              float* denom, float* alpha, const int* offsets, const int* ssrc,
                              int N, int E, hipStream_t stream) {
    constexpr int HF = HHEADS * F;
    edge_softmax<<<(N * HHEADS + 255) / 256, 256, 0, stream>>>(es, ed, offsets, ssrc, alpha,
                                                               denom, N);
    long total = (long)N * HF / 8;
    aggregate_kernel<F><<<(total + 255) / 256, 256, 0, stream>>>(hbuf, alpha, denom, offsets,
                                                                 ssrc, outbuf, N);
}

extern "C" void kernel_launch(void* const* d_in, const int* in_sizes, int n_in, void* d_out,
                              int out_size, void* d_ws, size_t ws_size, hipStream_t stream) {
    const float* x = (const float*)d_in[0];
    const int* ei = (const int*)d_in[1];
    const float* W1 = (const float*)d_in[2];
    const float* a1s = (const float*)d_in[3];
    const float* a1d = (const float*)d_in[4];
    const float* W2 = (const float*)d_in[5];
    const float* a2s = (const float*)d_in[6];
    const float* a2d = (const float*)d_in[7];
    const float* W3 = (const float*)d_in[8];
    const float* a3s = (const float*)d_in[9];
    const float* a3d = (const float*)d_in[10];
    const float* Wd = (const float*)d_in[11];
    const float* bd = (const float*)d_in[12];
    float* outp = (float*)d_out;

    const int N = in_sizes[0] / 11;
    const int E = in_sizes[1] / 2;
    const int* src = ei;
    const int* dst = ei + E;

    char* w = (char*)d_ws;
    size_t off = 0;
    auto A = [&](size_t bytes) {
        size_t o = off;
        off += (bytes + 255) & ~(size_t)255;
        return o;
    };
    __hip_bfloat16* bufH = (__hip_bfloat16*)(w + A((size_t)N * 384 * 2));  // bf16 h
    float* bufA = (float*)(w + A((size_t)N * 384 * 4));  // layer1 out (96), layer3 out (384)
    float* bufB = (float*)(w + A((size_t)N * 192 * 4));  // layer2 out
    float* es = (float*)(w + A((size_t)N * HHEADS * 4));
    float* ed = (float*)(w + A((size_t)N * HHEADS * 4));
    float* denom = (float*)(w + A((size_t)N * HHEADS * 4));
    float* alpha = (float*)(w + A((size_t)E * HHEADS * 4));
    float* wp = (float*)(w + A((size_t)192 * 384 * 4));  // repacked W, max layer3
    int* count = (int*)(w + A((size_t)(N + 1) * 4));
    int* cursor = (int*)(w + A((size_t)(N + 1) * 4));
    int* offsets = (int*)(w + A((size_t)(N + 1) * 4));
    int* ssrc = (int*)(w + A((size_t)E * 4));
    float* g = (float*)(w + A(384 * 4));

    // CSR build (by dst)
    hipMemsetAsync(count, 0, (size_t)N * 4, stream);
    hipMemsetAsync(cursor, 0, (size_t)N * 4, stream);
    hist_kernel<<<(E + 255) / 256, 256, 0, stream>>>(dst, count, E);
    scan_kernel<<<1, 1024, 0, stream>>>(count, offsets, N, E);
    scatter_kernel<<<(E + 255) / 256, 256, 0, stream>>>(src, dst, offsets, cursor, ssrc, E);

    // ---- layer 1 (FIN=11, F=16) ----
    repack_w<<<(11 * 96 + 255) / 256, 256, 0, stream>>>(W1, wp, 11, 16);
    {
        dim3 grid((96 + 63) / 64, (N + 63) / 64);
        gemm_small<64, 64, 32><<<grid, 256, 0, stream>>>(x, wp, bufH, N, 11, 96);
    }
    attn_terms<16><<<N, 96, 0, stream>>>(bufH, a1s, a1d, es, ed);
    run_edges_and_agg<16>(bufH, bufA, es, ed, denom, alpha, offsets, ssrc, N, E, stream);

    // ---- layer 2 (FIN=96, F=32) ----
    repack_w<<<(96 * 192 + 255) / 256, 256, 0, stream>>>(W2, wp, 96, 32);
    {
        dim3 grid((192 + 127) / 128, (N + 127) / 128);
        gemm_attn<32><<<grid, 256, 0, stream>>>(bufA, wp, bufH, a2s, a2d, es, ed, N, 96, 192);
    }
    run_edges_and_agg<32>(bufH, bufB, es, ed, denom, alpha, offsets, ssrc, N, E, stream);

    // ---- layer 3 (FIN=192, F=64) ----
    repack_w<<<(192 * 384 + 255) / 256, 256, 0, stream>>>(W3, wp, 192, 64);
    {
        dim3 grid((384 + 127) / 128, (N + 127) / 128);
        gemm_attn<64><<<grid, 256, 0, stream>>>(bufB, wp, bufH, a3s, a3d, es, ed, N, 192, 384);
    }
    run_edges_and_agg<64>(bufH, bufA, es, ed, denom, alpha, offsets, ssrc, N, E, stream);

    // sum-pool -> normalize -> dense
    hipMemsetAsync(g, 0, 384 * 4, stream);
    pool_kernel<<<256, 256, 0, stream>>>(bufA, g, N);
    final_kernel<<<1, 384, 0, stream>>>(g, Wd, bd, outp);
}